// Round 10
// baseline (985.045 us; speedup 1.0000x reference)
//
#include <hip/hip_runtime.h>

typedef unsigned short u16;
typedef __bf16 v8bf __attribute__((ext_vector_type(8)));
typedef float v4f __attribute__((ext_vector_type(4)));

// ---------- static device workspace ----------
__device__ __align__(256) unsigned char g_ws[140000000];

// ---------- bf16 helpers ----------
__device__ __forceinline__ float bf2f(u16 u) {
    union { unsigned int i; float f; } v; v.i = ((unsigned int)u) << 16; return v.f;
}
__device__ __forceinline__ u16 f2bf(float f) {
    union { float f; unsigned int i; } v; v.f = f;
    unsigned int r = v.i + 0x7FFFu + ((v.i >> 16) & 1u);
    return (u16)(r >> 16);
}
__device__ __forceinline__ float gelu_exact(float x) {
    return 0.5f * x * (1.0f + erff(x * 0.70710678118654752f));
}

// async global->LDS, 16 bytes per lane, dest = uniform base + lane*16
typedef const __attribute__((address_space(1))) void* gas_t;
typedef __attribute__((address_space(3))) void* las_t;
__device__ __forceinline__ void gload16(const u16* g, u16* lds_base_uniform) {
    __builtin_amdgcn_global_load_lds((gas_t)g, (las_t)lds_base_uniform, 16, 0, 0);
}

// yb -> (branch i, col-block blk) for the c-major blocked layout.
// CPB_i = floor(128/K_i) = {18,14,11,9,8,7}; NBLK_i = {15,19,24,29,32,37}; total 156.
__device__ __forceinline__ void yb_decode(int yb, int& i, int& blk) {
    if (yb < 15)      { i = 0; blk = yb; }
    else if (yb < 34) { i = 1; blk = yb - 15; }
    else if (yb < 58) { i = 2; blk = yb - 34; }
    else if (yb < 87) { i = 3; blk = yb - 58; }
    else if (yb < 119){ i = 4; blk = yb - 87; }
    else              { i = 5; blk = yb - 119; }
}

// ---------- fused prep: conv + permute_cm + permute_wp + transpose + zero ----------
#define NT 17
struct PrepArgs {
    const float* src[NT];
    unsigned int dstoff[NT];
    int n[NT];
    int cumblk[NT + 1];
    int nconv;
    const float* Woff; const float* boff;
    const float* Wm;   const float* bm;
    const float* Wp;   const float* x;
    u16* Wo_cm; u16* bo_cm; u16* Wm_cm; u16* bm_cm;
    u16* Wp_p;  u16* xT;
    float* res; float* zT;
};

// block ranges: [0,nconv) conv | [.,+4992) permute_cm | [.,+1536) wp |
//               [.,+1024) transpose | [.,+512) zero res/zT
__global__ __launch_bounds__(256) void prep_all(PrepArgs a, u16* __restrict__ arena) {
    __shared__ u16 tile[32][33];
    int bid = blockIdx.x;
    int tid = threadIdx.x;

    if (bid < a.nconv) {                          // ---- f32 -> bf16 conversions ----
        int t = 0;
        while (t < NT - 1 && bid >= a.cumblk[t + 1]) t++;
        int base = (bid - a.cumblk[t]) * 2048;
        const float* s = a.src[t];
        u16* d = arena + a.dstoff[t];
        int n = a.n[t];
#pragma unroll
        for (int j = 0; j < 8; j++) {
            int idx = base + j * 256 + tid;
            if (idx < n) d[idx] = f2bf(s[idx]);
        }
        return;
    }
    bid -= a.nconv;

    if (bid < 4992) {                             // ---- Woff/Wm c-major block-permute ----
        int yb = bid >> 5;
        int rest = bid & 31;
        int yblk = rest >> 1;                     // 0..15: 8 dst rows each
        int z = rest & 1;
        int i, blk; yb_decode(yb, i, blk);
        int K = 7 + 2 * i;
        int CPB = 128 / K;
        int c0b = blk * CPB;
        int CPBu = min(CPB, 256 - c0b);
        int jmax = CPBu * K;
        const float* Wsrc; const float* bsrc; u16* Wdst; u16* bdst;
        if (z == 0) { Wsrc = a.Woff; bsrc = a.boff; Wdst = a.Wo_cm; bdst = a.bo_cm; }
        else        { Wsrc = a.Wm;   bsrc = a.bm;   Wdst = a.Wm_cm; bdst = a.bm_cm; }
        long sbase = (long)i * 4352 * 256 + (long)(c0b * K) * 256;
        long dbase = (long)yb * 128 * 256;
#pragma unroll
        for (int jj = 0; jj < 8; jj++) {
            int j = yblk * 8 + jj;
            float v = (j < jmax) ? Wsrc[sbase + (long)j * 256 + tid] : 0.0f;
            Wdst[dbase + (long)j * 256 + tid] = f2bf(v);
            if (tid == 0)
                bdst[yb * 128 + j] = (j < jmax)
                    ? f2bf(bsrc[(long)i * 4352 + c0b * K + j]) : (u16)0;
        }
        return;
    }
    bid -= 4992;

    if (bid < 1536) {                             // ---- Wp [i][o][k] -> [o][i*256+k] ----
        int i = bid >> 8;
        int o = bid & 255;
        a.Wp_p[(long)o * 1536 + i * 256 + tid] =
            f2bf(a.Wp[(long)i * 65536 + o * 256 + tid]);
        return;
    }
    bid -= 1536;

    if (bid < 1024) {                             // ---- x [B,256,512] -> xT [B*512,256] ----
        int sblk = bid & 15;
        int rblk = (bid >> 4) & 7;
        int b = bid >> 7;
        const float* ip = a.x + (long)b * 256 * 512;
        u16* op = a.xT + (long)b * 256 * 512;
        int s0 = sblk * 32, r0 = rblk * 32;
        int tx = tid & 31, ty = tid >> 5;
#pragma unroll
        for (int j = 0; j < 4; j++) {
            int r = ty + j * 8;
            tile[r][tx] = f2bf(ip[(long)(r0 + r) * 512 + s0 + tx]);
        }
        __syncthreads();
#pragma unroll
        for (int j = 0; j < 4; j++) {
            int r = ty + j * 8;
            op[(long)(s0 + r) * 256 + r0 + tx] = tile[tx][r];
        }
        return;
    }
    bid -= 1024;

    {                                             // ---- zero res (256K f4) + zT (256K f4) ----
        v4f zv; zv[0] = 0.0f; zv[1] = 0.0f; zv[2] = 0.0f; zv[3] = 0.0f;
        v4f* r4 = (v4f*)a.res;
        v4f* z4 = (v4f*)a.zT;
#pragma unroll
        for (int it = 0; it < 4; it++) {
            long idx = (long)bid * 1024 + it * 256 + tid;   // 0 .. 524287
            if (idx < 262144) r4[idx] = zv;
            else              z4[idx - 262144] = zv;
        }
    }
}

// ---------- main GEMM (128x128 tile, BK=64, global_load_lds + XOR swizzle) ----------
// modes: 0 bf16, 1 gelu->bf16, 2 (acc+bias)*aux->bf16, 3 f32 store, 4 z0:gelu z1:plain,
//        5 split-K: z = K-chunk, atomicAdd into pre-zeroed f32 out (bias only z==0)
__global__ __launch_bounds__(256) void gemm_t(
    const u16* __restrict__ A, int lda, long az,
    const u16* __restrict__ W, int ldw, long wz,
    const u16* __restrict__ bias, long bz_,
    void* __restrict__ out, long oz,
    const u16* __restrict__ W2b, const u16* __restrict__ bias2, void* __restrict__ out2,
    const u16* __restrict__ aux, long xz,
    int Kd, int ldO, int mode)
{
    long z = blockIdx.z;
    if (W2b) {
        if (z == 1) { W = W2b; bias = bias2; out = out2; }
    } else {
        A += z * az; W += z * wz; bias += z * bz_;
        out = (void*)((char*)out + z * oz);
        if (aux) aux += z * xz;
    }
    if (mode == 4) mode = (z == 0) ? 1 : 0;
    if (mode == 5) out = (void*)((char*)out - z * oz);   // split-K: all z share out

    __shared__ alignas(16) u16 lA[128 * 64];
    __shared__ alignas(16) u16 lW[128 * 64];

    const int tid = threadIdx.x;
    const int wave = tid >> 6, lane = tid & 63;
    const int wm = wave >> 1, wn = wave & 1;
    const int lrow = lane & 15, quad = lane >> 4;
    const int m0 = blockIdx.x * 128;
    const int o0 = blockIdx.y * 128;

    const u16* Ab = A + (long)m0 * lda;
    const u16* Wb = W + (long)o0 * ldw;

    const int slr = lane >> 3;
    const int scp = lane & 7;
    const int ssrc = (scp ^ slr) * 8;

    v4f acc[4][4];
#pragma unroll
    for (int ms = 0; ms < 4; ms++)
#pragma unroll
        for (int ns = 0; ns < 4; ns++)
#pragma unroll
            for (int q = 0; q < 4; q++) acc[ms][ns][q] = 0.0f;

    for (int k0 = 0; k0 < Kd; k0 += 64) {
        __syncthreads();
#pragma unroll
        for (int j = 0; j < 4; j++) {
            int rb = wave * 4 + j;
            int row = rb * 8 + slr;
            gload16(Ab + (long)row * lda + k0 + ssrc, &lA[rb * 512]);
        }
#pragma unroll
        for (int j = 0; j < 4; j++) {
            int rb = wave * 4 + j;
            int row = rb * 8 + slr;
            gload16(Wb + (long)row * ldw + k0 + ssrc, &lW[rb * 512]);
        }
        __syncthreads();
#pragma unroll
        for (int ks = 0; ks < 2; ks++) {
            int c = ks * 4 + quad;
            int ph = (c ^ (lrow & 7)) * 8;
            v8bf af[4], wf[4];
#pragma unroll
            for (int ms = 0; ms < 4; ms++)
                af[ms] = *(const v8bf*)&lA[(wm * 64 + ms * 16 + lrow) * 64 + ph];
#pragma unroll
            for (int ns = 0; ns < 4; ns++)
                wf[ns] = *(const v8bf*)&lW[(wn * 64 + ns * 16 + lrow) * 64 + ph];
#pragma unroll
            for (int ms = 0; ms < 4; ms++)
#pragma unroll
                for (int ns = 0; ns < 4; ns++)
                    acc[ms][ns] = __builtin_amdgcn_mfma_f32_16x16x32_bf16(
                        af[ms], wf[ns], acc[ms][ns], 0, 0, 0);
        }
    }

    u16* o16 = (u16*)out;
    float* o32 = (float*)out;

#pragma unroll
    for (int ms = 0; ms < 4; ms++) {
#pragma unroll
        for (int ns = 0; ns < 4; ns++) {
            int o_g = o0 + wn * 64 + ns * 16 + lrow;
            float bval = (mode == 5 && z != 0) ? 0.0f : bf2f(bias[o_g]);
#pragma unroll
            for (int rg = 0; rg < 4; rg++) {
                int r_g = m0 + wm * 64 + ms * 16 + quad * 4 + rg;
                long oidx = (long)r_g * ldO + o_g;
                float v = acc[ms][ns][rg] + bval;
                if (mode == 0) {
                    o16[oidx] = f2bf(v);
                } else if (mode == 1) {
                    o16[oidx] = f2bf(gelu_exact(v));
                } else if (mode == 2) {
                    o16[oidx] = f2bf(v * bf2f(aux[oidx]));
                } else if (mode == 3) {
                    o32[oidx] = v;
                } else {
                    atomicAdd(&o32[oidx], v);
                }
            }
        }
    }
}

// ---------- fused off/ml GEMM + softmax + DCN gather (c-major blocked) ----------
// Runtime-K single body.  Tile 64 rows x 128 cols (CPBu channels x K taps), K-dim 256.
// GEMM: sequential W staging (Wo -> MFMA-O -> Wm in same buffer -> MFMA-M), so
// LDS = 8K(A) + 16K(W) = 24576 B -> 6 blocks/CU (was 4 at 40960).
// Epilogue: 2-phase pack/gather over 32-row halves (lml [32][131], odd dword stride);
// 128-row zero-padded V window staged by waves 2-3 during phase-0 pack; softmax +
// linear-interp gather from LDS with predicated global fallback (correctness-exact).
// 1-D grid 9984, XCD-partitioned: xcd=bid&7 owns a contiguous yb range.
__global__ __launch_bounds__(256, 6) void dcn_gemm_fused(
    const u16* __restrict__ xg,    // [4096][1536], branch i cols at i*256
    const u16* __restrict__ vbuf,  // [4096][1536], branch i cols at i*256
    const u16* __restrict__ Wo,    // [156*128][256] c-major blocked
    const u16* __restrict__ Wm,
    const u16* __restrict__ bo,    // [156*128]
    const u16* __restrict__ bm,
    u16* __restrict__ dcnT)        // [4096][1536]
{
    __shared__ alignas(16) unsigned char sh[24576];
    u16* lA = (u16*)sh;                          // [64][64] bf16   = 8192 B (GEMM)
    u16* lW = (u16*)(sh + 8192);                 // [128][64] bf16  = 16384 B (Wo then Wm)
    unsigned int* lml = (unsigned int*)sh;       // [32][131] u32   = 16768 B (epilogue)
    u16* lVw = (u16*)(sh + 16768);               // [128][CPBp] bf16 <= 4608 B (epilogue)

    int bid = blockIdx.x;
    int g = (bid & 7) * 1248 + (bid >> 3);
    int yb = g / 64;
    int m0 = (g & 63) * 64;
    int i, blk; yb_decode(yb, i, blk);
    const int K = 7 + 2 * i;
    const int CPB = 128 / K;
    const int CPBp = CPB + ((2 - CPB) & 3);      // {10,14,18}: odd dword strides
    const int c0 = blk * CPB;
    const int CPBu = min(CPB, 256 - c0);

    const int tid = threadIdx.x;
    const int wave = tid >> 6, lane = tid & 63;
    const int wm = wave >> 1, wn = wave & 1;     // wm: 32-row half, wn: 64-col half
    const int lrow = lane & 15, quad = lane >> 4;
    const int slr = lane >> 3, scp = lane & 7;
    const int ssrc = (scp ^ slr) * 8;

    const u16* Ab  = xg + (long)m0 * 1536 + i * 256;
    const u16* Wob = Wo + (long)yb * 128 * 256;
    const u16* Wmb = Wm + (long)yb * 128 * 256;

    v4f accO[2][4], accM[2][4];
#pragma unroll
    for (int ms = 0; ms < 2; ms++)
#pragma unroll
        for (int ns = 0; ns < 4; ns++)
#pragma unroll
            for (int q = 0; q < 4; q++) { accO[ms][ns][q] = 0.0f; accM[ms][ns][q] = 0.0f; }

    for (int k0 = 0; k0 < 256; k0 += 64) {
        __syncthreads();                         // prev phase done reading lA/lW
#pragma unroll
        for (int j = 0; j < 2; j++) {            // A: 8 row-blocks
            int rb = wave * 2 + j;
            int row = rb * 8 + slr;
            gload16(Ab + (long)row * 1536 + k0 + ssrc, &lA[rb * 512]);
        }
#pragma unroll
        for (int j = 0; j < 4; j++) {            // Wo: 16 row-blocks
            int rb = wave * 4 + j;
            int row = rb * 8 + slr;
            gload16(Wob + (long)row * 256 + k0 + ssrc, &lW[rb * 512]);
        }
        __syncthreads();
#pragma unroll
        for (int ks = 0; ks < 2; ks++) {         // MFMA-O
            int c = ks * 4 + quad;
            int ph = (c ^ (lrow & 7)) * 8;
            v8bf af[2], wof[4];
#pragma unroll
            for (int ms = 0; ms < 2; ms++)
                af[ms] = *(const v8bf*)&lA[(wm * 32 + ms * 16 + lrow) * 64 + ph];
#pragma unroll
            for (int ns = 0; ns < 4; ns++)
                wof[ns] = *(const v8bf*)&lW[(wn * 64 + ns * 16 + lrow) * 64 + ph];
#pragma unroll
            for (int ms = 0; ms < 2; ms++)
#pragma unroll
                for (int ns = 0; ns < 4; ns++)
                    accO[ms][ns] = __builtin_amdgcn_mfma_f32_16x16x32_bf16(
                        af[ms], wof[ns], accO[ms][ns], 0, 0, 0);
        }
        __syncthreads();                         // MFMA-O done reading lW
#pragma unroll
        for (int j = 0; j < 4; j++) {            // Wm overwrites lW
            int rb = wave * 4 + j;
            int row = rb * 8 + slr;
            gload16(Wmb + (long)row * 256 + k0 + ssrc, &lW[rb * 512]);
        }
        __syncthreads();
#pragma unroll
        for (int ks = 0; ks < 2; ks++) {         // MFMA-M (lA still valid)
            int c = ks * 4 + quad;
            int ph = (c ^ (lrow & 7)) * 8;
            v8bf af[2], wmf[4];
#pragma unroll
            for (int ms = 0; ms < 2; ms++)
                af[ms] = *(const v8bf*)&lA[(wm * 32 + ms * 16 + lrow) * 64 + ph];
#pragma unroll
            for (int ns = 0; ns < 4; ns++)
                wmf[ns] = *(const v8bf*)&lW[(wn * 64 + ns * 16 + lrow) * 64 + ph];
#pragma unroll
            for (int ms = 0; ms < 2; ms++)
#pragma unroll
                for (int ns = 0; ns < 4; ns++)
                    accM[ms][ns] = __builtin_amdgcn_mfma_f32_16x16x32_bf16(
                        af[ms], wmf[ns], accM[ms][ns], 0, 0, 0);
        }
    }
    __syncthreads();                             // staging bufs dead; reuse LDS

    // ---- epilogue, 2 phases of 32 rows.  Phase 0: waves 0-1 pack rows [0,32)
    //      while waves 2-3 stage the V window; then all gather rows [0,32);
    //      phase 1: waves 2-3 pack rows [32,64); all gather. ----
    const int b = m0 >> 9;
    const u16* vbase = vbuf + ((long)b * 512) * 1536 + i * 256 + c0;
    const int ws = (m0 & 511) - 32;              // window rows [ws, ws+128)
    const float khalf = (float)(K - 1) * 0.5f;
    const int np2 = 32 * CPBu;
    const unsigned int inv = (0x400000u + (unsigned)CPBu - 1) / (unsigned)CPBu;
    u16* dpb = dcnT + (long)m0 * 1536 + i * 256 + c0;

#pragma unroll
    for (int phase = 0; phase < 2; phase++) {
        if (phase == 0 && wave >= 2) {
            // V window stage (128 threads, one row each)
            int row = tid - 128;
            int labs = ws + row;
            bool inb = (labs >= 0 && labs < 512);
            const u16* vr = vbase + (long)labs * 1536;
            u16* lvr = lVw + row * CPBp;
            for (int cc = 0; cc < CPBu; cc++)
                lvr[cc] = inb ? vr[cc] : (u16)0;
        }
        if (wm == phase) {
            // pack this half's rows into lml [32][131]
#pragma unroll
            for (int ns = 0; ns < 4; ns++) {
                int j = wn * 64 + ns * 16 + lrow;
                float bov = bf2f(bo[yb * 128 + j]);
                float bmv = bf2f(bm[yb * 128 + j]);
#pragma unroll
                for (int ms = 0; ms < 2; ms++)
#pragma unroll
                    for (int rg = 0; rg < 4; rg++) {
                        int r = ms * 16 + quad * 4 + rg;   // local 0..31
                        unsigned int pk =
                            ((unsigned int)f2bf(accM[ms][ns][rg] + bmv) << 16)
                          | (unsigned int)f2bf(accO[ms][ns][rg] + bov);
                        lml[r * 131 + j] = pk;
                    }
            }
        }
        __syncthreads();

        // gather this half's rows
        for (int pair = tid; pair < np2; pair += 256) {
            int r = (int)(((unsigned)pair * inv) >> 22);
            int cc = pair - r * CPBu;
            int rgl = phase * 32 + r;            // row within 64-row tile
            const unsigned int* lp = &lml[r * 131 + cc * K];
            float lf = (float)((m0 & 511) + rgl) - khalf;
            float se = 0.0f, av = 0.0f;
            for (int k = 0; k < K; k++) {
                unsigned int w32 = lp[k];
                float e = __expf(bf2f((u16)(w32 >> 16)));
                float p = lf + (float)k + bf2f((u16)(w32 & 0xffffu));
                float p0 = floorf(p);
                float wgt = p - p0;
                int ia = (int)p0;
                int rel = ia - ws;
                float v0, v1;
                if ((unsigned)rel < 127u) {
                    v0 = bf2f(lVw[rel * CPBp + cc]);
                    v1 = bf2f(lVw[(rel + 1) * CPBp + cc]);
                } else {
                    v0 = (ia >= 0 && ia < 512) ? bf2f(vbase[(long)ia * 1536 + cc]) : 0.0f;
                    v1 = (ia >= -1 && ia < 511) ? bf2f(vbase[(long)(ia + 1) * 1536 + cc]) : 0.0f;
                }
                se += e;
                av += e * (v0 + wgt * (v1 - v0));
            }
            dpb[(long)rgl * 1536 + cc] = f2bf(av / se);
        }
        __syncthreads();                         // gather done reading lml before overwrite
    }
}

// ---------- residual + LayerNorm -> tn ----------
__global__ __launch_bounds__(256) void ln_kernel(
    const u16* __restrict__ xT, const float* __restrict__ res,
    const u16* __restrict__ ls, const u16* __restrict__ g, const u16* __restrict__ bb,
    u16* __restrict__ tnT)
{
    int r = blockIdx.x, c = threadIdx.x;
    long idx = (long)r * 256 + c;
    float y = bf2f(xT[idx]) + bf2f(ls[c]) * res[idx];

    __shared__ float red[8];
    int wave = c >> 6, lane = c & 63;
    float s = y;
#pragma unroll
    for (int m = 32; m; m >>= 1) s += __shfl_xor(s, m, 64);
    if (lane == 0) red[wave] = s;
    __syncthreads();
    float mu = (red[0] + red[1] + red[2] + red[3]) * (1.0f / 256.0f);
    float d = y - mu;
    float s2 = d * d;
#pragma unroll
    for (int m = 32; m; m >>= 1) s2 += __shfl_xor(s2, m, 64);
    if (lane == 0) red[4 + wave] = s2;
    __syncthreads();
    float var = (red[4] + red[5] + red[6] + red[7]) * (1.0f / 256.0f);
    float rstd = rsqrtf(var + 1e-6f);
    tnT[idx] = f2bf(d * rstd * bf2f(g[c]) + bf2f(bb[c]));
}

// ---------- final (zT f32 from split-K W2; bf16 round-trip matches old path) ----------
__global__ __launch_bounds__(256) void final_out(
    const float* __restrict__ x, const float* __restrict__ res, const float* __restrict__ zT,
    const u16* __restrict__ ls, const u16* __restrict__ g2, float* __restrict__ out)
{
    __shared__ float tile[32][33];
    int b = blockIdx.z;
    int l0 = blockIdx.x * 32, c0 = blockIdx.y * 32;
    int tx = threadIdx.x & 31, ty = threadIdx.x >> 5;
#pragma unroll
    for (int j = 0; j < 4; j++) {
        int l = ty + j * 8;
        long ridx = ((long)b * 512 + l0 + l) * 256 + c0 + tx;
        int c = c0 + tx;
        float s = bf2f(ls[c]) * res[ridx] + bf2f(g2[c]) * bf2f(f2bf(zT[ridx]));
        if (!(s > -0.04f && s < 0.04f)) s = 0.0f;
        tile[l][tx] = s;
    }
    __syncthreads();
#pragma unroll
    for (int j = 0; j < 4; j++) {
        int cc = ty + j * 8;
        long oidx = ((long)b * 256 + c0 + cc) * 512 + l0 + tx;
        out[oidx] = x[oidx] + tile[tx][cc];
    }
}

// ---------- launch ----------
extern "C" void kernel_launch(void* const* d_in, const int* in_sizes, int n_in,
                              void* d_out, int out_size, void* d_ws, size_t ws_size,
                              hipStream_t stream)
{
    const int Cc = 256, Ll = 512, NP = 6, HID = 1024, Nr = 4096;
    const int YB = 156;                 // c-major col-blocks total
    const float* x = (const float*)d_in[0];

    void* base = nullptr;
    (void)hipGetSymbolAddress(&base, HIP_SYMBOL(g_ws));
    char* wsp = (char*)base;

    // arena: Wa Wvd Wod Wv W1 W2 | ba bvd bod bv bp ls g2 lng lnb b1 b2
    static const int t_n[NT] = {
        393216, 393216, 393216, 393216, 262144, 262144,
        1536, 1536, 1536, 1536, 1536, 256, 256, 256, 256, 1024, 256
    };
    static const int t_src[NT] = {
        1, 3, 9, 11, 19, 21,
        2, 4, 10, 12, 14, 15, 16, 17, 18, 20, 22
    };
    PrepArgs pa;
    unsigned int off = 0;
    int cum = 0;
    unsigned int t_off[NT];
    for (int t = 0; t < NT; t++) {
        pa.src[t] = (const float*)d_in[t_src[t]];
        pa.n[t] = t_n[t];
        pa.dstoff[t] = off;
        t_off[t] = off;
        pa.cumblk[t] = cum;
        off += (unsigned int)t_n[t];
        cum += (t_n[t] + 2047) / 2048;
    }
    pa.cumblk[NT] = cum;
    pa.nconv = cum;
    u16* arena = (u16*)wsp;
    size_t woff = ((size_t)off * 2 + 255) & ~(size_t)255;

    auto alloc = [&](size_t bytes) -> void* {
        void* p = wsp + woff;
        woff += (bytes + 255) & ~(size_t)255;
        return p;
    };
    const long NC = (long)Nr * Cc;               // 1,048,576
    const long NI = (long)Nr * 1536;
    u16*   xT   = (u16*)alloc(NC * 2);
    float* res  = (float*)alloc(NC * 4);
    u16*   xg   = (u16*)alloc(NI * 2);
    u16*   vv   = (u16*)alloc(NI * 2);
    u16*   vbuf = (u16*)alloc(NI * 2);
    u16*   dcnb = (u16*)alloc(NI * 2);
    u16*   tnT  = (u16*)alloc(NC * 2);
    u16*   hT   = (u16*)alloc((size_t)Nr * HID * 2);
    float* zT   = (float*)alloc(NC * 4);
    u16*   Wp_p = (u16*)alloc((size_t)Cc * 1536 * 2);
    u16*   Wo_cm = (u16*)alloc((size_t)YB * 128 * Cc * 2);   // 10.2 MB
    u16*   Wm_cm = (u16*)alloc((size_t)YB * 128 * Cc * 2);
    u16*   bo_cm = (u16*)alloc((size_t)YB * 128 * 2);
    u16*   bm_cm = (u16*)alloc((size_t)YB * 128 * 2);
    u16*   ubuf = xg;

    u16* Wa_b  = arena + t_off[0];
    u16* Wvd_b = arena + t_off[1];
    u16* Wod_b = arena + t_off[2];
    u16* Wv_b  = arena + t_off[3];
    u16* W1_b  = arena + t_off[4];
    u16* W2_b  = arena + t_off[5];
    u16* ba_b  = arena + t_off[6];
    u16* bvd_b = arena + t_off[7];
    u16* bod_b = arena + t_off[8];
    u16* bv_b  = arena + t_off[9];
    u16* bp_b  = arena + t_off[10];
    u16* ls_b  = arena + t_off[11];
    u16* g2_b  = arena + t_off[12];
    u16* lng_b = arena + t_off[13];
    u16* lnb_b = arena + t_off[14];
    u16* b1_b  = arena + t_off[15];
    u16* b2_b  = arena + t_off[16];

    pa.Woff = (const float*)d_in[5]; pa.boff = (const float*)d_in[6];
    pa.Wm   = (const float*)d_in[7]; pa.bm   = (const float*)d_in[8];
    pa.Wp   = (const float*)d_in[13]; pa.x   = x;
    pa.Wo_cm = Wo_cm; pa.bo_cm = bo_cm; pa.Wm_cm = Wm_cm; pa.bm_cm = bm_cm;
    pa.Wp_p = Wp_p; pa.xT = xT;
    pa.res = res; pa.zT = zT;

    const long CC2 = (long)Cc * Cc;

    // 0) fused prep: conv + permute_cm + permute_wp + transpose + zero res/zT
    int nprep = cum + 4992 + 1536 + 1024 + 512;
    prep_all<<<dim3(nprep), 256, 0, stream>>>(pa, arena);

    // 1) xg (gelu) + vv (plain) in one z=2 dispatch (shared A = xT)
    gemm_t<<<dim3(Nr / 128, 1536 / 128, 2), 256, 0, stream>>>(
        xT, Cc, 0, Wa_b, Cc, 0, ba_b, 0, xg, 0,
        Wv_b, bv_b, vv, nullptr, 0, Cc, 1536, 4);
    // 2) v (z-batched over branches)
    gemm_t<<<dim3(Nr / 128, Cc / 128, NP), 256, 0, stream>>>(
        xg, 1536, 256, Wvd_b, Cc, CC2, bvd_b, 256, vbuf, 512,
        nullptr, nullptr, nullptr, nullptr, 0, Cc, 1536, 0);

    // 3) fused off/ml GEMM + softmax + DCN gather (all branches, one dispatch)
    dcn_gemm_fused<<<dim3(64 * YB), 256, 0, stream>>>(
        xg, vbuf, Wo_cm, Wm_cm, bo_cm, bm_cm, dcnb);

    // 4) u (z-batched), p (K=1536 split into 4 x 384, atomic f32)
    gemm_t<<<dim3(Nr / 128, Cc / 128, NP), 256, 0, stream>>>(
        dcnb, 1536, 256, Wod_b, Cc, CC2, bod_b, 256, ubuf, 512,
        nullptr, nullptr, nullptr, vv, 256, Cc, 1536, 2);
    gemm_t<<<dim3(Nr / 128, Cc / 128, 4), 256, 0, stream>>>(
        ubuf, 1536, 384, Wp_p, 1536, 384, bp_b, 0, res, 0,
        nullptr, nullptr, nullptr, nullptr, 0, 384, Cc, 5);

    // 5) LN + MLP (W2 split-K 4 x 256 into f32 zT)
    ln_kernel<<<dim3(Nr), 256, 0, stream>>>(xT, res, ls_b, lng_b, lnb_b, tnT);
    gemm_t<<<dim3(Nr / 128, HID / 128, 1), 256, 0, stream>>>(
        tnT, Cc, 0, W1_b, Cc, 0, b1_b, 0, hT, 0,
        nullptr, nullptr, nullptr, nullptr, 0, Cc, HID, 1);
    gemm_t<<<dim3(Nr / 128, Cc / 128, 4), 256, 0, stream>>>(
        hT, HID, 256, W2_b, HID, 256, b2_b, 0, zT, 0,
        nullptr, nullptr, nullptr, nullptr, 0, 256, Cc, 5);
    // 6) final
    final_out<<<dim3(Ll / 32, Cc / 32, 8), 256, 0, stream>>>(
        x, res, zT, ls_b, g2_b, (float*)d_out);
}

// Round 11
// 464.066 us; speedup vs baseline: 2.1226x; 2.1226x over previous
//
#include <hip/hip_runtime.h>

typedef unsigned short u16;
typedef __bf16 v8bf __attribute__((ext_vector_type(8)));
typedef float v4f __attribute__((ext_vector_type(4)));

// ---------- static device workspace ----------
__device__ __align__(256) unsigned char g_ws[140000000];

// ---------- bf16 helpers ----------
__device__ __forceinline__ float bf2f(u16 u) {
    union { unsigned int i; float f; } v; v.i = ((unsigned int)u) << 16; return v.f;
}
__device__ __forceinline__ u16 f2bf(float f) {
    union { float f; unsigned int i; } v; v.f = f;
    unsigned int r = v.i + 0x7FFFu + ((v.i >> 16) & 1u);
    return (u16)(r >> 16);
}
__device__ __forceinline__ float gelu_exact(float x) {
    return 0.5f * x * (1.0f + erff(x * 0.70710678118654752f));
}

// async global->LDS, 16 bytes per lane, dest = uniform base + lane*16
typedef const __attribute__((address_space(1))) void* gas_t;
typedef __attribute__((address_space(3))) void* las_t;
__device__ __forceinline__ void gload16(const u16* g, u16* lds_base_uniform) {
    __builtin_amdgcn_global_load_lds((gas_t)g, (las_t)lds_base_uniform, 16, 0, 0);
}

// yb -> (branch i, col-block blk) for the c-major blocked layout.
// CPB_i = floor(128/K_i) = {18,14,11,9,8,7}; NBLK_i = {15,19,24,29,32,37}; total 156.
__device__ __forceinline__ void yb_decode(int yb, int& i, int& blk) {
    if (yb < 15)      { i = 0; blk = yb; }
    else if (yb < 34) { i = 1; blk = yb - 15; }
    else if (yb < 58) { i = 2; blk = yb - 34; }
    else if (yb < 87) { i = 3; blk = yb - 58; }
    else if (yb < 119){ i = 4; blk = yb - 87; }
    else              { i = 5; blk = yb - 119; }
}

// ---------- fused prep: conv + permute_cm + permute_wp + transpose + zero ----------
#define NT 17
struct PrepArgs {
    const float* src[NT];
    unsigned int dstoff[NT];
    int n[NT];
    int cumblk[NT + 1];
    int nconv;
    const float* Woff; const float* boff;
    const float* Wm;   const float* bm;
    const float* Wp;   const float* x;
    u16* Wo_cm; u16* bo_cm; u16* Wm_cm; u16* bm_cm;
    u16* Wp_p;  u16* xT;
    float* res; float* zT;
};

// block ranges: [0,nconv) conv | [.,+4992) permute_cm | [.,+1536) wp |
//               [.,+1024) transpose | [.,+512) zero res/zT
__global__ __launch_bounds__(256) void prep_all(PrepArgs a, u16* __restrict__ arena) {
    __shared__ u16 tile[32][33];
    int bid = blockIdx.x;
    int tid = threadIdx.x;

    if (bid < a.nconv) {                          // ---- f32 -> bf16 conversions ----
        int t = 0;
        while (t < NT - 1 && bid >= a.cumblk[t + 1]) t++;
        int base = (bid - a.cumblk[t]) * 2048;
        const float* s = a.src[t];
        u16* d = arena + a.dstoff[t];
        int n = a.n[t];
#pragma unroll
        for (int j = 0; j < 8; j++) {
            int idx = base + j * 256 + tid;
            if (idx < n) d[idx] = f2bf(s[idx]);
        }
        return;
    }
    bid -= a.nconv;

    if (bid < 4992) {                             // ---- Woff/Wm c-major block-permute ----
        int yb = bid >> 5;
        int rest = bid & 31;
        int yblk = rest >> 1;                     // 0..15: 8 dst rows each
        int z = rest & 1;
        int i, blk; yb_decode(yb, i, blk);
        int K = 7 + 2 * i;
        int CPB = 128 / K;
        int c0b = blk * CPB;
        int CPBu = min(CPB, 256 - c0b);
        int jmax = CPBu * K;
        const float* Wsrc; const float* bsrc; u16* Wdst; u16* bdst;
        if (z == 0) { Wsrc = a.Woff; bsrc = a.boff; Wdst = a.Wo_cm; bdst = a.bo_cm; }
        else        { Wsrc = a.Wm;   bsrc = a.bm;   Wdst = a.Wm_cm; bdst = a.bm_cm; }
        long sbase = (long)i * 4352 * 256 + (long)(c0b * K) * 256;
        long dbase = (long)yb * 128 * 256;
#pragma unroll
        for (int jj = 0; jj < 8; jj++) {
            int j = yblk * 8 + jj;
            float v = (j < jmax) ? Wsrc[sbase + (long)j * 256 + tid] : 0.0f;
            Wdst[dbase + (long)j * 256 + tid] = f2bf(v);
            if (tid == 0)
                bdst[yb * 128 + j] = (j < jmax)
                    ? f2bf(bsrc[(long)i * 4352 + c0b * K + j]) : (u16)0;
        }
        return;
    }
    bid -= 4992;

    if (bid < 1536) {                             // ---- Wp [i][o][k] -> [o][i*256+k] ----
        int i = bid >> 8;
        int o = bid & 255;
        a.Wp_p[(long)o * 1536 + i * 256 + tid] =
            f2bf(a.Wp[(long)i * 65536 + o * 256 + tid]);
        return;
    }
    bid -= 1536;

    if (bid < 1024) {                             // ---- x [B,256,512] -> xT [B*512,256] ----
        int sblk = bid & 15;
        int rblk = (bid >> 4) & 7;
        int b = bid >> 7;
        const float* ip = a.x + (long)b * 256 * 512;
        u16* op = a.xT + (long)b * 256 * 512;
        int s0 = sblk * 32, r0 = rblk * 32;
        int tx = tid & 31, ty = tid >> 5;
#pragma unroll
        for (int j = 0; j < 4; j++) {
            int r = ty + j * 8;
            tile[r][tx] = f2bf(ip[(long)(r0 + r) * 512 + s0 + tx]);
        }
        __syncthreads();
#pragma unroll
        for (int j = 0; j < 4; j++) {
            int r = ty + j * 8;
            op[(long)(s0 + r) * 256 + r0 + tx] = tile[tx][r];
        }
        return;
    }
    bid -= 1024;

    {                                             // ---- zero res (256K f4) + zT (256K f4) ----
        v4f zv; zv[0] = 0.0f; zv[1] = 0.0f; zv[2] = 0.0f; zv[3] = 0.0f;
        v4f* r4 = (v4f*)a.res;
        v4f* z4 = (v4f*)a.zT;
#pragma unroll
        for (int it = 0; it < 4; it++) {
            long idx = (long)bid * 1024 + it * 256 + tid;   // 0 .. 524287
            if (idx < 262144) r4[idx] = zv;
            else              z4[idx - 262144] = zv;
        }
    }
}

// ---------- main GEMM (128x128 tile, BK=64, global_load_lds + XOR swizzle) ----------
// modes: 0 bf16, 1 gelu->bf16, 2 (acc+bias)*aux->bf16, 3 f32 store, 4 z0:gelu z1:plain,
//        5 split-K: z = K-chunk, atomicAdd into pre-zeroed f32 out (bias only z==0)
__global__ __launch_bounds__(256) void gemm_t(
    const u16* __restrict__ A, int lda, long az,
    const u16* __restrict__ W, int ldw, long wz,
    const u16* __restrict__ bias, long bz_,
    void* __restrict__ out, long oz,
    const u16* __restrict__ W2b, const u16* __restrict__ bias2, void* __restrict__ out2,
    const u16* __restrict__ aux, long xz,
    int Kd, int ldO, int mode)
{
    long z = blockIdx.z;
    if (W2b) {
        if (z == 1) { W = W2b; bias = bias2; out = out2; }
    } else {
        A += z * az; W += z * wz; bias += z * bz_;
        out = (void*)((char*)out + z * oz);
        if (aux) aux += z * xz;
    }
    if (mode == 4) mode = (z == 0) ? 1 : 0;
    if (mode == 5) out = (void*)((char*)out - z * oz);   // split-K: all z share out

    __shared__ alignas(16) u16 lA[128 * 64];
    __shared__ alignas(16) u16 lW[128 * 64];

    const int tid = threadIdx.x;
    const int wave = tid >> 6, lane = tid & 63;
    const int wm = wave >> 1, wn = wave & 1;
    const int lrow = lane & 15, quad = lane >> 4;
    const int m0 = blockIdx.x * 128;
    const int o0 = blockIdx.y * 128;

    const u16* Ab = A + (long)m0 * lda;
    const u16* Wb = W + (long)o0 * ldw;

    const int slr = lane >> 3;
    const int scp = lane & 7;
    const int ssrc = (scp ^ slr) * 8;

    v4f acc[4][4];
#pragma unroll
    for (int ms = 0; ms < 4; ms++)
#pragma unroll
        for (int ns = 0; ns < 4; ns++)
#pragma unroll
            for (int q = 0; q < 4; q++) acc[ms][ns][q] = 0.0f;

    for (int k0 = 0; k0 < Kd; k0 += 64) {
        __syncthreads();
#pragma unroll
        for (int j = 0; j < 4; j++) {
            int rb = wave * 4 + j;
            int row = rb * 8 + slr;
            gload16(Ab + (long)row * lda + k0 + ssrc, &lA[rb * 512]);
        }
#pragma unroll
        for (int j = 0; j < 4; j++) {
            int rb = wave * 4 + j;
            int row = rb * 8 + slr;
            gload16(Wb + (long)row * ldw + k0 + ssrc, &lW[rb * 512]);
        }
        __syncthreads();
#pragma unroll
        for (int ks = 0; ks < 2; ks++) {
            int c = ks * 4 + quad;
            int ph = (c ^ (lrow & 7)) * 8;
            v8bf af[4], wf[4];
#pragma unroll
            for (int ms = 0; ms < 4; ms++)
                af[ms] = *(const v8bf*)&lA[(wm * 64 + ms * 16 + lrow) * 64 + ph];
#pragma unroll
            for (int ns = 0; ns < 4; ns++)
                wf[ns] = *(const v8bf*)&lW[(wn * 64 + ns * 16 + lrow) * 64 + ph];
#pragma unroll
            for (int ms = 0; ms < 4; ms++)
#pragma unroll
                for (int ns = 0; ns < 4; ns++)
                    acc[ms][ns] = __builtin_amdgcn_mfma_f32_16x16x32_bf16(
                        af[ms], wf[ns], acc[ms][ns], 0, 0, 0);
        }
    }

    u16* o16 = (u16*)out;
    float* o32 = (float*)out;

#pragma unroll
    for (int ms = 0; ms < 4; ms++) {
#pragma unroll
        for (int ns = 0; ns < 4; ns++) {
            int o_g = o0 + wn * 64 + ns * 16 + lrow;
            float bval = (mode == 5 && z != 0) ? 0.0f : bf2f(bias[o_g]);
#pragma unroll
            for (int rg = 0; rg < 4; rg++) {
                int r_g = m0 + wm * 64 + ms * 16 + quad * 4 + rg;
                long oidx = (long)r_g * ldO + o_g;
                float v = acc[ms][ns][rg] + bval;
                if (mode == 0) {
                    o16[oidx] = f2bf(v);
                } else if (mode == 1) {
                    o16[oidx] = f2bf(gelu_exact(v));
                } else if (mode == 2) {
                    o16[oidx] = f2bf(v * bf2f(aux[oidx]));
                } else if (mode == 3) {
                    o32[oidx] = v;
                } else {
                    atomicAdd(&o32[oidx], v);
                }
            }
        }
    }
}

// ---------- fused off/ml GEMM + softmax + DCN gather (c-major blocked) ----------
// Runtime-K single body.  Tile 64 rows x 128 cols (CPBu channels x K taps), K-dim 256.
// Epilogue: pack (ml,off)+bias bf16 pairs into LDS [r][131] (odd dword stride);
// stage a 128-row zero-padded V WINDOW around the diagonal; softmax + linear-interp
// gather from LDS with a predicated global fallback for out-of-window taps
// (correctness-exact).  LDS = 40960 B -> 4 blocks/CU (register-bound anyway:
// 64 VGPR + 64 AGPR acc = 128 unified regs/wave -> 4 waves/SIMD is the ceiling).
// 1-D grid 9984, XCD-partitioned: xcd=bid&7 owns a contiguous yb range.
__global__ __launch_bounds__(256, 4) void dcn_gemm_fused(
    const u16* __restrict__ xg,    // [4096][1536], branch i cols at i*256
    const u16* __restrict__ vbuf,  // [4096][1536], branch i cols at i*256
    const u16* __restrict__ Wo,    // [156*128][256] c-major blocked
    const u16* __restrict__ Wm,
    const u16* __restrict__ bo,    // [156*128]
    const u16* __restrict__ bm,
    u16* __restrict__ dcnT)        // [4096][1536]
{
    __shared__ alignas(16) unsigned char sh[40960];
    u16* lA  = (u16*)sh;                         // 64x64 bf16   = 8192 B (GEMM)
    u16* lWo = (u16*)(sh + 8192);                // 128x64 bf16  = 16384 B (GEMM)
    u16* lWm = (u16*)(sh + 24576);               // 128x64 bf16  = 16384 B (GEMM)
    unsigned int* lml = (unsigned int*)sh;       // [64 r][131] u32 = 33536 B (epilogue)
    u16* lVw = (u16*)(sh + 33536);               // [128][CPBp] window <= 4608 B (epilogue)

    int bid = blockIdx.x;
    int g = (bid & 7) * 1248 + (bid >> 3);
    int yb = g / 64;
    int m0 = (g & 63) * 64;
    int i, blk; yb_decode(yb, i, blk);
    const int K = 7 + 2 * i;
    const int CPB = 128 / K;
    const int CPBp = CPB + ((2 - CPB) & 3);      // {10,14,18}: odd dword strides
    const int c0 = blk * CPB;
    const int CPBu = min(CPB, 256 - c0);

    const int tid = threadIdx.x;
    const int wave = tid >> 6, lane = tid & 63;
    const int wm = wave >> 1, wn = wave & 1;     // wm: 32-row half, wn: 64-col half
    const int lrow = lane & 15, quad = lane >> 4;
    const int slr = lane >> 3, scp = lane & 7;
    const int ssrc = (scp ^ slr) * 8;

    const u16* Ab  = xg + (long)m0 * 1536 + i * 256;
    const u16* Wob = Wo + (long)yb * 128 * 256;
    const u16* Wmb = Wm + (long)yb * 128 * 256;

    v4f accO[2][4], accM[2][4];
#pragma unroll
    for (int ms = 0; ms < 2; ms++)
#pragma unroll
        for (int ns = 0; ns < 4; ns++)
#pragma unroll
            for (int q = 0; q < 4; q++) { accO[ms][ns][q] = 0.0f; accM[ms][ns][q] = 0.0f; }

    for (int k0 = 0; k0 < 256; k0 += 64) {
        __syncthreads();
#pragma unroll
        for (int j = 0; j < 2; j++) {            // A: 8 row-blocks
            int rb = wave * 2 + j;
            int row = rb * 8 + slr;
            gload16(Ab + (long)row * 1536 + k0 + ssrc, &lA[rb * 512]);
        }
#pragma unroll
        for (int j = 0; j < 4; j++) {            // Wo: 16 row-blocks
            int rb = wave * 4 + j;
            int row = rb * 8 + slr;
            gload16(Wob + (long)row * 256 + k0 + ssrc, &lWo[rb * 512]);
        }
#pragma unroll
        for (int j = 0; j < 4; j++) {            // Wm: 16 row-blocks
            int rb = wave * 4 + j;
            int row = rb * 8 + slr;
            gload16(Wmb + (long)row * 256 + k0 + ssrc, &lWm[rb * 512]);
        }
        __syncthreads();
#pragma unroll
        for (int ks = 0; ks < 2; ks++) {
            int c = ks * 4 + quad;
            int ph = (c ^ (lrow & 7)) * 8;
            v8bf af[2], wof[4], wmf[4];
#pragma unroll
            for (int ms = 0; ms < 2; ms++)
                af[ms] = *(const v8bf*)&lA[(wm * 32 + ms * 16 + lrow) * 64 + ph];
#pragma unroll
            for (int ns = 0; ns < 4; ns++) {
                wof[ns] = *(const v8bf*)&lWo[(wn * 64 + ns * 16 + lrow) * 64 + ph];
                wmf[ns] = *(const v8bf*)&lWm[(wn * 64 + ns * 16 + lrow) * 64 + ph];
            }
#pragma unroll
            for (int ms = 0; ms < 2; ms++)
#pragma unroll
                for (int ns = 0; ns < 4; ns++) {
                    accO[ms][ns] = __builtin_amdgcn_mfma_f32_16x16x32_bf16(
                        af[ms], wof[ns], accO[ms][ns], 0, 0, 0);
                    accM[ms][ns] = __builtin_amdgcn_mfma_f32_16x16x32_bf16(
                        af[ms], wmf[ns], accM[ms][ns], 0, 0, 0);
                }
        }
    }
    __syncthreads();                             // staging bufs dead; reuse LDS

    // ---- V window stage (issued first; latency overlaps the pack below) ----
    const int b = m0 >> 9;
    const u16* vbase = vbuf + ((long)b * 512) * 1536 + i * 256 + c0;
    const int ws = (m0 & 511) - 32;              // window rows [ws, ws+128)
    {
        int row = tid & 127;
        int labs = ws + row;
        bool inb = (labs >= 0 && labs < 512);
        const u16* vr = vbase + (long)labs * 1536;
        u16* lvr = lVw + row * CPBp;
        for (int cc = (tid >> 7); cc < CPBu; cc += 2)
            lvr[cc] = inb ? vr[cc] : (u16)0;
    }

    // ---- pack (ml|off)+bias as bf16 pair, row-major [r][131] ----
#pragma unroll
    for (int ns = 0; ns < 4; ns++) {
        int j = wn * 64 + ns * 16 + lrow;
        float bov = bf2f(bo[yb * 128 + j]);
        float bmv = bf2f(bm[yb * 128 + j]);
#pragma unroll
        for (int ms = 0; ms < 2; ms++)
#pragma unroll
            for (int rg = 0; rg < 4; rg++) {
                int r = wm * 32 + ms * 16 + quad * 4 + rg;
                unsigned int pk = ((unsigned int)f2bf(accM[ms][ns][rg] + bmv) << 16)
                                | (unsigned int)f2bf(accO[ms][ns][rg] + bov);
                lml[r * 131 + j] = pk;
            }
    }
    __syncthreads();

    // ---- softmax + gather (window LDS fast path, global fallback) ----
    const float khalf = (float)(K - 1) * 0.5f;
    const int npairs = 64 * CPBu;
    const unsigned int inv = (0x400000u + (unsigned)CPBu - 1) / (unsigned)CPBu;
    u16* dpb = dcnT + (long)m0 * 1536 + i * 256 + c0;
    for (int pair = tid; pair < npairs; pair += 256) {
        int r = (int)(((unsigned)pair * inv) >> 22);
        int cc = pair - r * CPBu;
        const unsigned int* lp = &lml[r * 131 + cc * K];
        float lf = (float)((m0 & 511) + r) - khalf;
        float se = 0.0f, av = 0.0f;
        for (int k = 0; k < K; k++) {
            unsigned int w32 = lp[k];
            float e = __expf(bf2f((u16)(w32 >> 16)));
            float p = lf + (float)k + bf2f((u16)(w32 & 0xffffu));
            float p0 = floorf(p);
            float wgt = p - p0;
            int ia = (int)p0;
            int rel = ia - ws;
            float v0, v1;
            if ((unsigned)rel < 127u) {
                v0 = bf2f(lVw[rel * CPBp + cc]);
                v1 = bf2f(lVw[(rel + 1) * CPBp + cc]);
            } else {
                v0 = (ia >= 0 && ia < 512) ? bf2f(vbase[(long)ia * 1536 + cc]) : 0.0f;
                v1 = (ia >= -1 && ia < 511) ? bf2f(vbase[(long)(ia + 1) * 1536 + cc]) : 0.0f;
            }
            se += e;
            av += e * (v0 + wgt * (v1 - v0));
        }
        dpb[(long)r * 1536 + cc] = f2bf(av / se);
    }
}

// ---------- residual + LayerNorm -> tn ----------
__global__ __launch_bounds__(256) void ln_kernel(
    const u16* __restrict__ xT, const float* __restrict__ res,
    const u16* __restrict__ ls, const u16* __restrict__ g, const u16* __restrict__ bb,
    u16* __restrict__ tnT)
{
    int r = blockIdx.x, c = threadIdx.x;
    long idx = (long)r * 256 + c;
    float y = bf2f(xT[idx]) + bf2f(ls[c]) * res[idx];

    __shared__ float red[8];
    int wave = c >> 6, lane = c & 63;
    float s = y;
#pragma unroll
    for (int m = 32; m; m >>= 1) s += __shfl_xor(s, m, 64);
    if (lane == 0) red[wave] = s;
    __syncthreads();
    float mu = (red[0] + red[1] + red[2] + red[3]) * (1.0f / 256.0f);
    float d = y - mu;
    float s2 = d * d;
#pragma unroll
    for (int m = 32; m; m >>= 1) s2 += __shfl_xor(s2, m, 64);
    if (lane == 0) red[4 + wave] = s2;
    __syncthreads();
    float var = (red[4] + red[5] + red[6] + red[7]) * (1.0f / 256.0f);
    float rstd = rsqrtf(var + 1e-6f);
    tnT[idx] = f2bf(d * rstd * bf2f(g[c]) + bf2f(bb[c]));
}

// ---------- final (zT f32 from split-K W2; bf16 round-trip matches old path) ----------
__global__ __launch_bounds__(256) void final_out(
    const float* __restrict__ x, const float* __restrict__ res, const float* __restrict__ zT,
    const u16* __restrict__ ls, const u16* __restrict__ g2, float* __restrict__ out)
{
    __shared__ float tile[32][33];
    int b = blockIdx.z;
    int l0 = blockIdx.x * 32, c0 = blockIdx.y * 32;
    int tx = threadIdx.x & 31, ty = threadIdx.x >> 5;
#pragma unroll
    for (int j = 0; j < 4; j++) {
        int l = ty + j * 8;
        long ridx = ((long)b * 512 + l0 + l) * 256 + c0 + tx;
        int c = c0 + tx;
        float s = bf2f(ls[c]) * res[ridx] + bf2f(g2[c]) * bf2f(f2bf(zT[ridx]));
        if (!(s > -0.04f && s < 0.04f)) s = 0.0f;
        tile[l][tx] = s;
    }
    __syncthreads();
#pragma unroll
    for (int j = 0; j < 4; j++) {
        int cc = ty + j * 8;
        long oidx = ((long)b * 256 + c0 + cc) * 512 + l0 + tx;
        out[oidx] = x[oidx] + tile[tx][cc];
    }
}

// ---------- launch ----------
extern "C" void kernel_launch(void* const* d_in, const int* in_sizes, int n_in,
                              void* d_out, int out_size, void* d_ws, size_t ws_size,
                              hipStream_t stream)
{
    const int Cc = 256, Ll = 512, NP = 6, HID = 1024, Nr = 4096;
    const int YB = 156;                 // c-major col-blocks total
    const float* x = (const float*)d_in[0];

    void* base = nullptr;
    (void)hipGetSymbolAddress(&base, HIP_SYMBOL(g_ws));
    char* wsp = (char*)base;

    // arena: Wa Wvd Wod Wv W1 W2 | ba bvd bod bv bp ls g2 lng lnb b1 b2
    static const int t_n[NT] = {
        393216, 393216, 393216, 393216, 262144, 262144,
        1536, 1536, 1536, 1536, 1536, 256, 256, 256, 256, 1024, 256
    };
    static const int t_src[NT] = {
        1, 3, 9, 11, 19, 21,
        2, 4, 10, 12, 14, 15, 16, 17, 18, 20, 22
    };
    PrepArgs pa;
    unsigned int off = 0;
    int cum = 0;
    unsigned int t_off[NT];
    for (int t = 0; t < NT; t++) {
        pa.src[t] = (const float*)d_in[t_src[t]];
        pa.n[t] = t_n[t];
        pa.dstoff[t] = off;
        t_off[t] = off;
        pa.cumblk[t] = cum;
        off += (unsigned int)t_n[t];
        cum += (t_n[t] + 2047) / 2048;
    }
    pa.cumblk[NT] = cum;
    pa.nconv = cum;
    u16* arena = (u16*)wsp;
    size_t woff = ((size_t)off * 2 + 255) & ~(size_t)255;

    auto alloc = [&](size_t bytes) -> void* {
        void* p = wsp + woff;
        woff += (bytes + 255) & ~(size_t)255;
        return p;
    };
    const long NC = (long)Nr * Cc;               // 1,048,576
    const long NI = (long)Nr * 1536;
    u16*   xT   = (u16*)alloc(NC * 2);
    float* res  = (float*)alloc(NC * 4);
    u16*   xg   = (u16*)alloc(NI * 2);
    u16*   vv   = (u16*)alloc(NI * 2);
    u16*   vbuf = (u16*)alloc(NI * 2);
    u16*   dcnb = (u16*)alloc(NI * 2);
    u16*   tnT  = (u16*)alloc(NC * 2);
    u16*   hT   = (u16*)alloc((size_t)Nr * HID * 2);
    float* zT   = (float*)alloc(NC * 4);
    u16*   Wp_p = (u16*)alloc((size_t)Cc * 1536 * 2);
    u16*   Wo_cm = (u16*)alloc((size_t)YB * 128 * Cc * 2);   // 10.2 MB
    u16*   Wm_cm = (u16*)alloc((size_t)YB * 128 * Cc * 2);
    u16*   bo_cm = (u16*)alloc((size_t)YB * 128 * 2);
    u16*   bm_cm = (u16*)alloc((size_t)YB * 128 * 2);
    u16*   ubuf = xg;

    u16* Wa_b  = arena + t_off[0];
    u16* Wvd_b = arena + t_off[1];
    u16* Wod_b = arena + t_off[2];
    u16* Wv_b  = arena + t_off[3];
    u16* W1_b  = arena + t_off[4];
    u16* W2_b  = arena + t_off[5];
    u16* ba_b  = arena + t_off[6];
    u16* bvd_b = arena + t_off[7];
    u16* bod_b = arena + t_off[8];
    u16* bv_b  = arena + t_off[9];
    u16* bp_b  = arena + t_off[10];
    u16* ls_b  = arena + t_off[11];
    u16* g2_b  = arena + t_off[12];
    u16* lng_b = arena + t_off[13];
    u16* lnb_b = arena + t_off[14];
    u16* b1_b  = arena + t_off[15];
    u16* b2_b  = arena + t_off[16];

    pa.Woff = (const float*)d_in[5]; pa.boff = (const float*)d_in[6];
    pa.Wm   = (const float*)d_in[7]; pa.bm   = (const float*)d_in[8];
    pa.Wp   = (const float*)d_in[13]; pa.x   = x;
    pa.Wo_cm = Wo_cm; pa.bo_cm = bo_cm; pa.Wm_cm = Wm_cm; pa.bm_cm = bm_cm;
    pa.Wp_p = Wp_p; pa.xT = xT;
    pa.res = res; pa.zT = zT;

    const long CC2 = (long)Cc * Cc;

    // 0) fused prep: conv + permute_cm + permute_wp + transpose + zero res/zT
    int nprep = cum + 4992 + 1536 + 1024 + 512;
    prep_all<<<dim3(nprep), 256, 0, stream>>>(pa, arena);

    // 1) xg (gelu) + vv (plain) in one z=2 dispatch (shared A = xT)
    gemm_t<<<dim3(Nr / 128, 1536 / 128, 2), 256, 0, stream>>>(
        xT, Cc, 0, Wa_b, Cc, 0, ba_b, 0, xg, 0,
        Wv_b, bv_b, vv, nullptr, 0, Cc, 1536, 4);
    // 2) v (z-batched over branches)
    gemm_t<<<dim3(Nr / 128, Cc / 128, NP), 256, 0, stream>>>(
        xg, 1536, 256, Wvd_b, Cc, CC2, bvd_b, 256, vbuf, 512,
        nullptr, nullptr, nullptr, nullptr, 0, Cc, 1536, 0);

    // 3) fused off/ml GEMM + softmax + DCN gather (all branches, one dispatch)
    dcn_gemm_fused<<<dim3(64 * YB), 256, 0, stream>>>(
        xg, vbuf, Wo_cm, Wm_cm, bo_cm, bm_cm, dcnb);

    // 4) u (z-batched), p (K=1536 split into 4 x 384, atomic f32)
    gemm_t<<<dim3(Nr / 128, Cc / 128, NP), 256, 0, stream>>>(
        dcnb, 1536, 256, Wod_b, Cc, CC2, bod_b, 256, ubuf, 512,
        nullptr, nullptr, nullptr, vv, 256, Cc, 1536, 2);
    gemm_t<<<dim3(Nr / 128, Cc / 128, 4), 256, 0, stream>>>(
        ubuf, 1536, 384, Wp_p, 1536, 384, bp_b, 0, res, 0,
        nullptr, nullptr, nullptr, nullptr, 0, 384, Cc, 5);

    // 5) LN + MLP (W2 split-K 4 x 256 into f32 zT)
    ln_kernel<<<dim3(Nr), 256, 0, stream>>>(xT, res, ls_b, lng_b, lnb_b, tnT);
    gemm_t<<<dim3(Nr / 128, HID / 128, 1), 256, 0, stream>>>(
        tnT, Cc, 0, W1_b, Cc, 0, b1_b, 0, hT, 0,
        nullptr, nullptr, nullptr, nullptr, 0, Cc, HID, 1);
    gemm_t<<<dim3(Nr / 128, Cc / 128, 4), 256, 0, stream>>>(
        hT, HID, 256, W2_b, HID, 256, b2_b, 0, zT, 0,
        nullptr, nullptr, nullptr, nullptr, 0, 256, Cc, 5);
    // 6) final
    final_out<<<dim3(Ll / 32, Cc / 32, 8), 256, 0, stream>>>(
        x, res, zT, ls_b, g2_b, (float*)d_out);
}